// Round 1
// baseline (1140.696 us; speedup 1.0000x reference)
//
#include <hip/hip_runtime.h>
#include <hip/hip_bf16.h>
#include <math.h>

#define S_LEN 512
#define B_SZ  256
#define E_DIM 128
#define HHID  128
#define G4    512   // 4*HH
#define T_TAG 9
#define NR    (S_LEN * B_SZ)   // r = s*256 + b
#define VOCAB 5001

typedef __attribute__((ext_vector_type(8))) short bf16x8;
typedef __attribute__((ext_vector_type(4))) float f32x4;

__device__ __forceinline__ float bf2f(__hip_bfloat16 v) { return __bfloat162float(v); }
__device__ __forceinline__ float scrub0(float v) {       // inf/nan -> 0
    unsigned u = __float_as_uint(v);
    return (((u >> 23) & 0xFFu) == 0xFFu) ? 0.f : v;
}
__device__ __forceinline__ float frcp(float x) { return __builtin_amdgcn_rcpf(x); }
__device__ __forceinline__ float fsig(float x) { return frcp(1.f + __expf(-x)); }
__device__ __forceinline__ float ftanh(float x) {
    return 1.f - 2.f * frcp(1.f + __expf(2.f * x));
}

// ---- .bss scratch (~150 MB) ----
__device__ __hip_bfloat16 g_emb[VOCAB * E_DIM];
__device__ __hip_bfloat16 g_wih[2][G4 * E_DIM];    // rows permuted: n' = 4u+g
__device__ __hip_bfloat16 g_whh2[2][G4 * HHID];    // rows permuted: n' = 4u+g
__device__ __align__(16) float g_bias[2][G4];      // permuted
__device__ float g_wout[T_TAG * 256];
__device__ float g_bout[T_TAG];
__device__ float g_trans[T_TAG * T_TAG];
__device__ float g_start[T_TAG];
__device__ float g_end[T_TAG];
__device__ float g_maskf[B_SZ * S_LEN];
__device__ float g_em[(long)NR * T_TAG];
__device__ __align__(16) float g_hs[2][(long)NR * HHID];  // [(s*16+bg)*128+u]*16+m

// -------------------------------------------------------------------------
__global__ __launch_bounds__(256) void fill_out(float* out, int n) {
    const int i = blockIdx.x * 256 + threadIdx.x;
    if (i < n) out[i] = 0.f;
}

// -------------------------------------------------------------------------
// Canonicalize inputs (bf16/fp32 autodetect via mask). Gate permutation:
// row n' = 4u+g  <->  original torch gate row g*128+u.
// -------------------------------------------------------------------------
__global__ __launch_bounds__(256) void convert_kernel(
    const void* mask, const void* emb,
    const void* wih_f, const void* whh_f, const void* bih_f, const void* bhh_f,
    const void* wih_b, const void* whh_b, const void* bih_b, const void* bhh_b,
    const void* wout, const void* bout, const void* trans,
    const void* startt, const void* endt)
{
    const bool isb = (((const unsigned*)mask)[0] == 0x3F803F80u);
    auto ldf = [&](const void* p, long i) -> float {
        float v = isb ? bf2f(((const __hip_bfloat16*)p)[i]) : ((const float*)p)[i];
        return scrub0(v);
    };
    const long tid0   = (long)blockIdx.x * blockDim.x + threadIdx.x;
    const long stride = (long)gridDim.x * blockDim.x;

    for (long i = tid0; i < (long)VOCAB * E_DIM; i += stride)
        g_emb[i] = __float2bfloat16(ldf(emb, i));
    for (long i = tid0; i < (long)G4 * E_DIM; i += stride) {
        const int np = (int)(i >> 7), e = (int)(i & 127);
        const int g = np & 3, u = np >> 2;
        const long src = (long)(g * 128 + u) * E_DIM + e;
        g_wih[0][i] = __float2bfloat16(ldf(wih_f, src));
        g_wih[1][i] = __float2bfloat16(ldf(wih_b, src));
    }
    for (long i = tid0; i < (long)G4 * HHID; i += stride) {
        const int np = (int)(i >> 7), k = (int)(i & 127);
        const int g = np & 3, u = np >> 2;
        const long src = (long)(g * 128 + u) * HHID + k;
        g_whh2[0][i] = __float2bfloat16(ldf(whh_f, src));
        g_whh2[1][i] = __float2bfloat16(ldf(whh_b, src));
    }
    for (long i = tid0; i < G4; i += stride) {
        const int g = (int)i & 3, u = (int)i >> 2;
        const long src = g * 128 + u;
        g_bias[0][i] = ldf(bih_f, src) + ldf(bhh_f, src);
        g_bias[1][i] = ldf(bih_b, src) + ldf(bhh_b, src);
    }
    for (long i = tid0; i < T_TAG * 256; i += stride) g_wout[i] = ldf(wout, i);
    for (long i = tid0; i < T_TAG * T_TAG; i += stride) g_trans[i] = ldf(trans, i);
    for (long i = tid0; i < T_TAG; i += stride) {
        g_bout[i]  = ldf(bout, i);
        g_start[i] = ldf(startt, i);
        g_end[i]   = ldf(endt, i);
    }
    for (long i = tid0; i < (long)B_SZ * S_LEN; i += stride)
        g_maskf[i] = ldf(mask, i);
}

// -------------------------------------------------------------------------
// Fused MFMA scan, software-pipelined: during step s the block
//  (B) consumes px_s:  acc = px_s + Whh'@(h_hi+h_lo)^T     [8-chain, critical]
//  (C) produces px_{s+1} = bias + Wih'@emb_{s+1}^T          [independent of h]
//  (D) prefetches emb fragments for s+2                      [L2-resident]
// Lane (wv,quad,m16) tile t holds gates i,f,g,o (reg 0..3) of unit
// u=16wv+4t+quad, batch m16 -> c/h update fully in-lane. ONE barrier/step.
//
// Barrier is a raw s_barrier + lgkmcnt(0) ONLY: __syncthreads would drain
// vmcnt(0) every step, serializing the hsp global stores and killing the
// 2-step-ahead emb prefetch. Cross-wave hB visibility only needs lgkmcnt.
// -------------------------------------------------------------------------
__global__ __launch_bounds__(512, 1) void scan_mfma(const int* __restrict__ x)
{
    __shared__ __align__(16) unsigned short hB[2][2][16 * 16 * 8];  // 16 KB
    __shared__ int xO[S_LEN * 16];   // premultiplied emb element offsets (32 KB)

    const int bg = blockIdx.x, dir = blockIdx.y;
    const int tid  = threadIdx.x;
    const int lane = tid & 63, wv = tid >> 6;
    const int m16  = lane & 15, quad = lane >> 4;

    // persistent A fragments: Whh' + Wih' rows (lane&15 = n_local)
    bf16x8 W[4][4], V[4][4];
    f32x4 bias4[4];
    #pragma unroll
    for (int t = 0; t < 4; t++) {
        const int np = (wv * 4 + t) * 16 + m16;
        #pragma unroll
        for (int kk = 0; kk < 4; kk++) {
            W[t][kk] = *(const bf16x8*)&g_whh2[dir][(long)np * HHID + kk * 32 + quad * 8];
            V[t][kk] = *(const bf16x8*)&g_wih[dir][(long)np * E_DIM + kk * 32 + quad * 8];
        }
        const int u = 16 * wv + 4 * t + quad;
        const float4 b4 = *(const float4*)&g_bias[dir][4 * u];
        bias4[t] = (f32x4){b4.x, b4.y, b4.z, b4.w};
    }
    {   // stage premultiplied token offsets: xO[s*16+m] = x[bg*16+m][s] * E_DIM
        const bool x64 = ((x[1] | x[3] | x[5] | x[7]) == 0);
        for (int i = tid; i < S_LEN * 16; i += 512) {
            const int s = i >> 4, m = i & 15;
            const int ii = (bg * 16 + m) * S_LEN + s;
            xO[i] = (x64 ? x[2 * ii] : x[ii]) * E_DIM;
        }
    }
    for (int i = tid; i < 2 * 2 * 2048; i += 512) ((unsigned short*)hB)[i] = 0;
    float c[4] = {0.f, 0.f, 0.f, 0.f};
    __syncthreads();

    int se = dir ? (S_LEN - 1) : 0;
    const int step = dir ? -1 : 1;

    // px for step 0: bias + V@E(se0); then E <- fragments for step 1
    bf16x8 E[4];
    f32x4 px[4];
    {
        const int xo0 = xO[se * 16 + m16];
        #pragma unroll
        for (int kk = 0; kk < 4; kk++)
            E[kk] = *(const bf16x8*)&g_emb[(long)xo0 + kk * 32 + quad * 8];
        #pragma unroll
        for (int t = 0; t < 4; t++) {
            px[t] = bias4[t];
            #pragma unroll
            for (int kk = 0; kk < 4; kk++)
                px[t] = __builtin_amdgcn_mfma_f32_16x16x32_bf16(V[t][kk], E[kk], px[t], 0, 0, 0);
        }
        const int se1 = (S_LEN > 1) ? se + step : se;
        const int xo1 = xO[se1 * 16 + m16];
        #pragma unroll
        for (int kk = 0; kk < 4; kk++)
            E[kk] = *(const bf16x8*)&g_emb[(long)xo1 + kk * 32 + quad * 8];
    }

    // incremental hs store base: index ((se*16+bg)*128 + u0)*16 + m16,
    // cells at +0,+64,+128,+192; per-step delta = step*32768 floats
    float* hsp = &g_hs[dir][((long)(se * 16 + bg) * 128 + (16 * wv + quad)) * 16 + m16];
    const long hsd = (long)step * 32768;

    for (int it = 0; it < S_LEN; it++) {
        const int rd = it & 1, wr = rd ^ 1;
        const int se_next = (it + 1 < S_LEN) ? (se + step) : se;

        // (B) consume: acc = px + W@Hh + W@Hl  — the recurrent critical path
        bf16x8 Hh[4], Hl[4];
        #pragma unroll
        for (int kk = 0; kk < 4; kk++) {
            const int off = ((kk * 4 + quad) * 16 + m16) * 8;
            Hh[kk] = *(const bf16x8*)&hB[rd][0][off];
            Hl[kk] = *(const bf16x8*)&hB[rd][1][off];
        }
        f32x4 acc[4];
        #pragma unroll
        for (int t = 0; t < 4; t++) {
            acc[t] = px[t];
            #pragma unroll
            for (int kk = 0; kk < 4; kk++) {
                acc[t] = __builtin_amdgcn_mfma_f32_16x16x32_bf16(W[t][kk], Hh[kk], acc[t], 0, 0, 0);
                acc[t] = __builtin_amdgcn_mfma_f32_16x16x32_bf16(W[t][kk], Hl[kk], acc[t], 0, 0, 0);
            }
        }
        // (C) produce px for NEXT step (independent of h — fills MFMA pipe)
        #pragma unroll
        for (int t = 0; t < 4; t++) {
            px[t] = bias4[t];
            #pragma unroll
            for (int kk = 0; kk < 4; kk++)
                px[t] = __builtin_amdgcn_mfma_f32_16x16x32_bf16(V[t][kk], E[kk], px[t], 0, 0, 0);
        }
        // (D) prefetch emb fragments for step it+2 (L2-resident; stays in
        // flight across the raw barrier — no vmcnt drain)
        {
            const int se2 = (it + 2 < S_LEN) ? (se_next + step) : se_next;
            const int xo2 = xO[se2 * 16 + m16];
            #pragma unroll
            for (int kk = 0; kk < 4; kk++)
                E[kk] = *(const bf16x8*)&g_emb[(long)xo2 + kk * 32 + quad * 8];
        }
        // (E) in-lane gate activation + c/h update (reg: 0=i 1=f 2=g 3=o)
        #pragma unroll
        for (int t = 0; t < 4; t++) {
            const float iv = fsig(acc[t][0]);
            const float fv = fsig(acc[t][1]);
            const float gv = ftanh(acc[t][2]);
            const float ov = fsig(acc[t][3]);
            c[t] = fv * c[t] + iv * gv;
            const float h = ov * ftanh(c[t]);
            const int u = 16 * wv + 4 * t + quad;
            const unsigned ub = __float_as_uint(h);
            const unsigned hb_ = ub >> 16;
            const float hif = __uint_as_float(ub & 0xFFFF0000u);
            const unsigned lb_ = __float_as_uint(h - hif) >> 16;
            const int ha = (u >> 3) * 128 + m16 * 8 + (u & 7);
            hB[wr][0][ha] = (unsigned short)hb_;
            hB[wr][1][ha] = (unsigned short)lb_;
            hsp[t * 64] = h;                       // +0,+64,+128,+192
        }
        // --- raw barrier: wait only DS ops (hB writes/reads), leave global
        // stores (hsp) and emb prefetch (E) in flight across the barrier ---
        asm volatile("s_waitcnt lgkmcnt(0)" ::: "memory");
        __builtin_amdgcn_sched_barrier(0);
        __builtin_amdgcn_s_barrier();
        __builtin_amdgcn_sched_barrier(0);

        hsp += hsd;
        se = se_next;
    }
}

// -------------------------------------------------------------------------
// Bulk emission from hs layout: block = (s,bg) tile [128u x 16m], staged in
// LDS; thread (m, j<9) dots 256-k. em[r*9+j] includes bout.
// -------------------------------------------------------------------------
__global__ __launch_bounds__(256, 4) void emission_kernel()
{
    __shared__ float hfL[2048], hbL[2048];
    __shared__ float Wsh[T_TAG][256];
    __shared__ float bo[T_TAG];
    const int tid = threadIdx.x, blk = blockIdx.x;   // 0..8191 = s*16+bg
    for (int i = tid; i < T_TAG * 256; i += 256) Wsh[i >> 8][i & 255] = g_wout[i];
    if (tid < T_TAG) bo[tid] = g_bout[tid];
    const float* hf = &g_hs[0][(long)blk * 2048];
    const float* hb = &g_hs[1][(long)blk * 2048];
    for (int i = tid; i < 2048; i += 256) { hfL[i] = hf[i]; hbL[i] = hb[i]; }
    __syncthreads();

    const int m = tid & 15, j = tid >> 4;
    if (j < T_TAG) {
        float acc = bo[j];
        #pragma unroll 4
        for (int u = 0; u < 128; u++)
            acc += hfL[u * 16 + m] * Wsh[j][u] + hbL[u * 16 + m] * Wsh[j][128 + u];
        const int r = (blk >> 4) * 256 + (blk & 15) * 16 + m;   // s*256 + b
        g_em[(long)r * T_TAG + j] = scrub0(acc);
    }
}

// -------------------------------------------------------------------------
// Viterbi: 1 wave per batch element (lanes 0..8 = tags), score broadcast via
// wave shfl — NO per-step barrier. Strict-> argmax = jnp first-max.
// -------------------------------------------------------------------------
__global__ __launch_bounds__(256, 2)
void viterbi_kernel(float* __restrict__ out, int out_size)
{
    __shared__ unsigned char bp[4][S_LEN][T_TAG];
    const int wid  = threadIdx.x >> 6;
    const int lane = threadIdx.x & 63;
    const int b  = blockIdx.x * 4 + wid;
    const int jj = (lane < T_TAG) ? lane : 0;

    float tcol[T_TAG];
    #pragma unroll
    for (int i = 0; i < T_TAG; i++) tcol[i] = g_trans[i * T_TAG + jj];

    float score[T_TAG];
    {
        const float m0 = g_maskf[b * S_LEN + 0];
        #pragma unroll
        for (int i = 0; i < T_TAG; i++)
            score[i] = g_start[i] + g_em[(long)b * T_TAG + i] * m0;
    }
    float e = g_em[((long)1 * B_SZ + b) * T_TAG + jj];
    float m = g_maskf[b * S_LEN + 1];

    for (int s = 1; s < S_LEN; s++) {
        float en = 0.f, mn = 0.f;
        if (s + 1 < S_LEN) {   // prefetch next step
            en = g_em[((long)(s + 1) * B_SZ + b) * T_TAG + jj];
            mn = g_maskf[b * S_LEN + s + 1];
        }
        float best = score[0] + tcol[0];
        int arg = 0;
        #pragma unroll
        for (int i = 1; i < T_TAG; i++) {
            const float cnd = score[i] + tcol[i];
            if (cnd > best) { best = cnd; arg = i; }
        }
        float ns; int nbp;
        if (m > 0.f) { ns = best + e * m; nbp = arg; }
        else         { ns = score[jj];    nbp = jj;  }
        if (lane < T_TAG) bp[wid][s][jj] = (unsigned char)nbp;
        #pragma unroll
        for (int i = 0; i < T_TAG; i++) score[i] = __shfl(ns, i, 64);
        e = en; m = mn;
    }
    #pragma unroll
    for (int i = 0; i < T_TAG; i++) score[i] += g_end[i];

    __syncthreads();   // bp visible for backtrace

    if (lane == 0) {
        float bs = score[0]; int last = 0;
        #pragma unroll
        for (int i = 1; i < T_TAG; i++)
            if (score[i] > bs) { bs = score[i]; last = i; }
        {
            const unsigned u = __float_as_uint(bs);
            if (((u >> 23) & 0xFFu) == 0xFFu) bs = -100.f;
        }
        if ((long)B_SZ * S_LEN + b < out_size)
            out[(long)B_SZ * S_LEN + b] = bs;
        int tag = last;
        if (tag < 0) tag = 0; if (tag > 8) tag = 8;
        out[(long)b * S_LEN + (S_LEN - 1)] = (float)tag;
        for (int s2 = S_LEN - 1; s2 >= 1; s2--) {
            tag = bp[wid][s2][tag];
            if (tag < 0) tag = 0; if (tag > 8) tag = 8;
            out[(long)b * S_LEN + (s2 - 1)] = (float)tag;
        }
    }
}

// -------------------------------------------------------------------------
extern "C" void kernel_launch(void* const* d_in, const int* in_sizes, int n_in,
                              void* d_out, int out_size, void* d_ws, size_t ws_size,
                              hipStream_t stream) {
    const int* x = (const int*)d_in[0];
    float* out = (float*)d_out;

    fill_out<<<(out_size + 255) / 256, 256, 0, stream>>>(out, out_size);
    convert_kernel<<<512, 256, 0, stream>>>(
        d_in[1], d_in[2], d_in[3], d_in[4], d_in[5], d_in[6],
        d_in[7], d_in[8], d_in[9], d_in[10], d_in[11], d_in[12],
        d_in[13], d_in[14], d_in[15]);
    scan_mfma<<<dim3(16, 2), 512, 0, stream>>>(x);
    emission_kernel<<<8192, 256, 0, stream>>>();
    viterbi_kernel<<<64, 256, 0, stream>>>(out, out_size);
}

// Round 2
// 993.733 us; speedup vs baseline: 1.1479x; 1.1479x over previous
//
#include <hip/hip_runtime.h>
#include <hip/hip_bf16.h>
#include <math.h>

#define S_LEN 512
#define B_SZ  256
#define E_DIM 128
#define HHID  128
#define G4    512   // 4*HH
#define T_TAG 9
#define NR    (S_LEN * B_SZ)   // r = s*256 + b
#define VOCAB 5001

typedef __attribute__((ext_vector_type(8))) short bf16x8;
typedef __attribute__((ext_vector_type(4))) float f32x4;

__device__ __forceinline__ float bf2f(__hip_bfloat16 v) { return __bfloat162float(v); }
__device__ __forceinline__ float scrub0(float v) {       // inf/nan -> 0
    unsigned u = __float_as_uint(v);
    return (((u >> 23) & 0xFFu) == 0xFFu) ? 0.f : v;
}
__device__ __forceinline__ float frcp(float x) { return __builtin_amdgcn_rcpf(x); }
__device__ __forceinline__ float fsig(float x) { return frcp(1.f + __expf(-x)); }
__device__ __forceinline__ float ftanh(float x) {
    return 1.f - 2.f * frcp(1.f + __expf(2.f * x));
}

// ---- .bss scratch ----
__device__ __hip_bfloat16 g_emb[VOCAB * E_DIM];
__device__ __hip_bfloat16 g_wih[2][G4 * E_DIM];    // rows permuted: n' = 4u+g
__device__ __hip_bfloat16 g_whh2[2][G4 * HHID];    // rows permuted: n' = 4u+g
__device__ __align__(16) float g_bias[2][G4];      // permuted
__device__ float g_wout[T_TAG * 256];
__device__ float g_bout[T_TAG];
__device__ float g_trans[T_TAG * T_TAG];
__device__ float g_start[T_TAG];
__device__ float g_end[T_TAG];
__device__ float g_maskf[B_SZ * S_LEN];
__device__ float g_em[(long)NR * T_TAG];
__device__ __align__(16) float g_hs[2][(long)NR * HHID];  // [(s*16+bg)*128+u]*16+m
// px = bias + Wih'@emb, precomputed for all steps. Layout:
// [dir][s][bg][u][m16][g] — scan reads 1KB contiguous per wave per tile.
__device__ __align__(16) float g_px[(long)2 * S_LEN * 16 * 128 * 16 * 4];  // 512 MiB

// -------------------------------------------------------------------------
__global__ __launch_bounds__(256) void fill_out(float* out, int n) {
    const int i = blockIdx.x * 256 + threadIdx.x;
    if (i < n) out[i] = 0.f;
}

// -------------------------------------------------------------------------
// Canonicalize inputs (bf16/fp32 autodetect via mask). Gate permutation:
// row n' = 4u+g  <->  original torch gate row g*128+u.
// -------------------------------------------------------------------------
__global__ __launch_bounds__(256) void convert_kernel(
    const void* mask, const void* emb,
    const void* wih_f, const void* whh_f, const void* bih_f, const void* bhh_f,
    const void* wih_b, const void* whh_b, const void* bih_b, const void* bhh_b,
    const void* wout, const void* bout, const void* trans,
    const void* startt, const void* endt)
{
    const bool isb = (((const unsigned*)mask)[0] == 0x3F803F80u);
    auto ldf = [&](const void* p, long i) -> float {
        float v = isb ? bf2f(((const __hip_bfloat16*)p)[i]) : ((const float*)p)[i];
        return scrub0(v);
    };
    const long tid0   = (long)blockIdx.x * blockDim.x + threadIdx.x;
    const long stride = (long)gridDim.x * blockDim.x;

    for (long i = tid0; i < (long)VOCAB * E_DIM; i += stride)
        g_emb[i] = __float2bfloat16(ldf(emb, i));
    for (long i = tid0; i < (long)G4 * E_DIM; i += stride) {
        const int np = (int)(i >> 7), e = (int)(i & 127);
        const int g = np & 3, u = np >> 2;
        const long src = (long)(g * 128 + u) * E_DIM + e;
        g_wih[0][i] = __float2bfloat16(ldf(wih_f, src));
        g_wih[1][i] = __float2bfloat16(ldf(wih_b, src));
    }
    for (long i = tid0; i < (long)G4 * HHID; i += stride) {
        const int np = (int)(i >> 7), k = (int)(i & 127);
        const int g = np & 3, u = np >> 2;
        const long src = (long)(g * 128 + u) * HHID + k;
        g_whh2[0][i] = __float2bfloat16(ldf(whh_f, src));
        g_whh2[1][i] = __float2bfloat16(ldf(whh_b, src));
    }
    for (long i = tid0; i < G4; i += stride) {
        const int g = (int)i & 3, u = (int)i >> 2;
        const long src = g * 128 + u;
        g_bias[0][i] = ldf(bih_f, src) + ldf(bhh_f, src);
        g_bias[1][i] = ldf(bih_b, src) + ldf(bhh_b, src);
    }
    for (long i = tid0; i < T_TAG * 256; i += stride) g_wout[i] = ldf(wout, i);
    for (long i = tid0; i < T_TAG * T_TAG; i += stride) g_trans[i] = ldf(trans, i);
    for (long i = tid0; i < T_TAG; i += stride) {
        g_bout[i]  = ldf(bout, i);
        g_start[i] = ldf(startt, i);
        g_end[i]   = ldf(endt, i);
    }
    for (long i = tid0; i < (long)B_SZ * S_LEN; i += stride)
        g_maskf[i] = ldf(mask, i);
}

// -------------------------------------------------------------------------
// Bulk input projection on ALL CUs: px[dir][s][bg] = bias + Wih'@emb^T,
// bit-exact replication of the old in-scan px MFMA sequence. Block = 512
// threads (8 waves, 4 tiles each), grid (16 bg, 2 dir, 8 s-chunks).
// -------------------------------------------------------------------------
__global__ __launch_bounds__(512, 2) void px_gemm(const int* __restrict__ x)
{
    const int bg = blockIdx.x, dir = blockIdx.y, sc = blockIdx.z;
    const int tid  = threadIdx.x;
    const int lane = tid & 63, wv = tid >> 6;
    const int m16  = lane & 15, quad = lane >> 4;

    bf16x8 V[4][4];
    f32x4 bias4[4];
    #pragma unroll
    for (int t = 0; t < 4; t++) {
        const int np = (wv * 4 + t) * 16 + m16;
        #pragma unroll
        for (int kk = 0; kk < 4; kk++)
            V[t][kk] = *(const bf16x8*)&g_wih[dir][(long)np * E_DIM + kk * 32 + quad * 8];
        const int u = 16 * wv + 4 * t + quad;
        const float4 b4 = *(const float4*)&g_bias[dir][4 * u];
        bias4[t] = (f32x4){b4.x, b4.y, b4.z, b4.w};
    }
    const bool x64 = ((x[1] | x[3] | x[5] | x[7]) == 0);
    const int b = bg * 16 + m16;
    const int s0 = sc * 64;
    for (int s = s0; s < s0 + 64; s++) {
        const int ii = b * S_LEN + s;
        const int xo = (x64 ? x[2 * ii] : x[ii]) * E_DIM;
        bf16x8 E[4];
        #pragma unroll
        for (int kk = 0; kk < 4; kk++)
            E[kk] = *(const bf16x8*)&g_emb[(long)xo + kk * 32 + quad * 8];
        #pragma unroll
        for (int t = 0; t < 4; t++) {
            f32x4 px = bias4[t];
            #pragma unroll
            for (int kk = 0; kk < 4; kk++)
                px = __builtin_amdgcn_mfma_f32_16x16x32_bf16(V[t][kk], E[kk], px, 0, 0, 0);
            const int u = 16 * wv + 4 * t + quad;
            const long idx = (((long)(dir * S_LEN + s) * 16 + bg) * 128 + u) * 64 + m16 * 4;
            *(f32x4*)&g_px[idx] = px;
        }
    }
}

// -------------------------------------------------------------------------
// Recurrence-only MFMA scan: 16 waves (1024 thr), 2 gate-tiles per wave ->
// 4 waves/SIMD interleave the dep chains the old 2-wave config serialized.
// px comes from g_px (2-step parity prefetch, rides across the raw barrier).
// Lane (wv,quad,m16) tile t: gates i,f,g,o (reg 0..3) of u=8wv+4t+quad,
// batch m16. ONE lgkm-only barrier/step (vmcnt stays in flight).
// -------------------------------------------------------------------------
#define SCAN_STEP(RD, PX)                                                      \
  {                                                                            \
    const int wr_ = (RD) ^ 1;                                                  \
    bf16x8 Hh_[4], Hl_[4];                                                     \
    _Pragma("unroll")                                                          \
    for (int kk = 0; kk < 4; kk++) {                                           \
        const int off_ = ((kk * 4 + quad) * 16 + m16) * 8;                     \
        Hh_[kk] = *(const bf16x8*)&hB[RD][0][off_];                            \
        Hl_[kk] = *(const bf16x8*)&hB[RD][1][off_];                            \
    }                                                                          \
    _Pragma("unroll")                                                          \
    for (int t = 0; t < 2; t++) {                                              \
        _Pragma("unroll")                                                      \
        for (int kk = 0; kk < 4; kk++) {                                       \
            PX[t] = __builtin_amdgcn_mfma_f32_16x16x32_bf16(W[t][kk], Hh_[kk], PX[t], 0, 0, 0); \
            PX[t] = __builtin_amdgcn_mfma_f32_16x16x32_bf16(W[t][kk], Hl_[kk], PX[t], 0, 0, 0); \
        }                                                                      \
    }                                                                          \
    _Pragma("unroll")                                                          \
    for (int t = 0; t < 2; t++) {                                              \
        const float iv = fsig(PX[t][0]);                                       \
        const float fv = fsig(PX[t][1]);                                       \
        const float gv = ftanh(PX[t][2]);                                      \
        const float ov = fsig(PX[t][3]);                                       \
        c[t] = fv * c[t] + iv * gv;                                            \
        const float h = ov * ftanh(c[t]);                                      \
        const unsigned ub = __float_as_uint(h);                                \
        const unsigned hb_ = ub >> 16;                                         \
        const float hif = __uint_as_float(ub & 0xFFFF0000u);                   \
        const unsigned lb_ = __float_as_uint(h - hif) >> 16;                   \
        const int ha = wv * 128 + m16 * 8 + 4 * t + quad;                      \
        hB[wr_][0][ha] = (unsigned short)hb_;                                  \
        hB[wr_][1][ha] = (unsigned short)lb_;                                  \
        hsp[t * 64] = h;                                                       \
    }                                                                          \
    {   /* reload PX for step itv+2 (parity double-buffer, clamped) */         \
        const float* pf_ = (itv + 2 < S_LEN) ? (pxp + 2 * pxd) : pxp;          \
        PX[0] = *(const f32x4*)(pf_ + 0);                                      \
        PX[1] = *(const f32x4*)(pf_ + 256);                                    \
    }                                                                          \
    asm volatile("s_waitcnt lgkmcnt(0)" ::: "memory");                         \
    __builtin_amdgcn_sched_barrier(0);                                         \
    __builtin_amdgcn_s_barrier();                                              \
    __builtin_amdgcn_sched_barrier(0);                                         \
    hsp += hsd; pxp += pxd; itv++;                                             \
  }

__global__ __launch_bounds__(1024, 4) void scan_mfma()
{
    __shared__ __align__(16) unsigned short hB[2][2][16 * 16 * 8];  // 16 KB

    const int bg = blockIdx.x, dir = blockIdx.y;
    const int tid  = threadIdx.x;
    const int lane = tid & 63, wv = tid >> 6;        // wv 0..15
    const int m16  = lane & 15, quad = lane >> 4;

    // persistent A fragments: Whh' rows (2 tiles of 16 rows per wave)
    bf16x8 W[2][4];
    #pragma unroll
    for (int t = 0; t < 2; t++) {
        const int np = (wv * 2 + t) * 16 + m16;
        #pragma unroll
        for (int kk = 0; kk < 4; kk++)
            W[t][kk] = *(const bf16x8*)&g_whh2[dir][(long)np * HHID + kk * 32 + quad * 8];
    }
    for (int i = tid; i < 2 * 2 * 2048; i += 1024) ((unsigned short*)hB)[i] = 0;
    float c[2] = {0.f, 0.f};

    const int se0  = dir ? (S_LEN - 1) : 0;
    const int step = dir ? -1 : 1;
    const int u0   = 8 * wv + quad;

    // px pointers: current-step base + per-step delta (s-stride = 131072 f32)
    const float* pxp = &g_px[(((long)(dir * S_LEN + se0) * 16 + bg) * 128 + u0) * 64 + m16 * 4];
    const long pxd = (long)step * 131072;

    f32x4 pxA[2], pxB[2];
    pxA[0] = *(const f32x4*)(pxp + 0);
    pxA[1] = *(const f32x4*)(pxp + 256);
    {
        const float* p1 = pxp + pxd;
        pxB[0] = *(const f32x4*)(p1 + 0);
        pxB[1] = *(const f32x4*)(p1 + 256);
    }

    // incremental hs store base: ((se*16+bg)*128 + u0)*16 + m16, tiles at
    // +0,+64 floats; per-step delta = step*32768 floats
    float* hsp = &g_hs[dir][((long)(se0 * 16 + bg) * 128 + u0) * 16 + m16];
    const long hsd = (long)step * 32768;

    int itv = 0;
    __syncthreads();

    for (int it = 0; it < S_LEN; it += 2) {
        SCAN_STEP(0, pxA)      // even step: read hB[0], write hB[1]
        SCAN_STEP(1, pxB)      // odd step:  read hB[1], write hB[0]
    }
}

// -------------------------------------------------------------------------
// Bulk emission from hs layout: block = (s,bg) tile [128u x 16m], staged in
// LDS; thread (m, j<9) dots 256-k. em[r*9+j] includes bout.
// -------------------------------------------------------------------------
__global__ __launch_bounds__(256, 4) void emission_kernel()
{
    __shared__ float hfL[2048], hbL[2048];
    __shared__ float Wsh[T_TAG][256];
    __shared__ float bo[T_TAG];
    const int tid = threadIdx.x, blk = blockIdx.x;   // 0..8191 = s*16+bg
    for (int i = tid; i < T_TAG * 256; i += 256) Wsh[i >> 8][i & 255] = g_wout[i];
    if (tid < T_TAG) bo[tid] = g_bout[tid];
    const float* hf = &g_hs[0][(long)blk * 2048];
    const float* hb = &g_hs[1][(long)blk * 2048];
    for (int i = tid; i < 2048; i += 256) { hfL[i] = hf[i]; hbL[i] = hb[i]; }
    __syncthreads();

    const int m = tid & 15, j = tid >> 4;
    if (j < T_TAG) {
        float acc = bo[j];
        #pragma unroll 4
        for (int u = 0; u < 128; u++)
            acc += hfL[u * 16 + m] * Wsh[j][u] + hbL[u * 16 + m] * Wsh[j][128 + u];
        const int r = (blk >> 4) * 256 + (blk & 15) * 16 + m;   // s*256 + b
        g_em[(long)r * T_TAG + j] = scrub0(acc);
    }
}

// -------------------------------------------------------------------------
// Viterbi: 1 wave per batch element (lanes 0..8 = tags), score broadcast via
// wave shfl — NO per-step barrier. Strict-> argmax = jnp first-max.
// -------------------------------------------------------------------------
__global__ __launch_bounds__(256, 2)
void viterbi_kernel(float* __restrict__ out, int out_size)
{
    __shared__ unsigned char bp[4][S_LEN][T_TAG];
    const int wid  = threadIdx.x >> 6;
    const int lane = threadIdx.x & 63;
    const int b  = blockIdx.x * 4 + wid;
    const int jj = (lane < T_TAG) ? lane : 0;

    float tcol[T_TAG];
    #pragma unroll
    for (int i = 0; i < T_TAG; i++) tcol[i] = g_trans[i * T_TAG + jj];

    float score[T_TAG];
    {
        const float m0 = g_maskf[b * S_LEN + 0];
        #pragma unroll
        for (int i = 0; i < T_TAG; i++)
            score[i] = g_start[i] + g_em[(long)b * T_TAG + i] * m0;
    }
    float e = g_em[((long)1 * B_SZ + b) * T_TAG + jj];
    float m = g_maskf[b * S_LEN + 1];

    for (int s = 1; s < S_LEN; s++) {
        float en = 0.f, mn = 0.f;
        if (s + 1 < S_LEN) {   // prefetch next step
            en = g_em[((long)(s + 1) * B_SZ + b) * T_TAG + jj];
            mn = g_maskf[b * S_LEN + s + 1];
        }
        float best = score[0] + tcol[0];
        int arg = 0;
        #pragma unroll
        for (int i = 1; i < T_TAG; i++) {
            const float cnd = score[i] + tcol[i];
            if (cnd > best) { best = cnd; arg = i; }
        }
        float ns; int nbp;
        if (m > 0.f) { ns = best + e * m; nbp = arg; }
        else         { ns = score[jj];    nbp = jj;  }
        if (lane < T_TAG) bp[wid][s][jj] = (unsigned char)nbp;
        #pragma unroll
        for (int i = 0; i < T_TAG; i++) score[i] = __shfl(ns, i, 64);
        e = en; m = mn;
    }
    #pragma unroll
    for (int i = 0; i < T_TAG; i++) score[i] += g_end[i];

    __syncthreads();   // bp visible for backtrace

    if (lane == 0) {
        float bs = score[0]; int last = 0;
        #pragma unroll
        for (int i = 1; i < T_TAG; i++)
            if (score[i] > bs) { bs = score[i]; last = i; }
        {
            const unsigned u = __float_as_uint(bs);
            if (((u >> 23) & 0xFFu) == 0xFFu) bs = -100.f;
        }
        if ((long)B_SZ * S_LEN + b < out_size)
            out[(long)B_SZ * S_LEN + b] = bs;
        int tag = last;
        if (tag < 0) tag = 0; if (tag > 8) tag = 8;
        out[(long)b * S_LEN + (S_LEN - 1)] = (float)tag;
        for (int s2 = S_LEN - 1; s2 >= 1; s2--) {
            tag = bp[wid][s2][tag];
            if (tag < 0) tag = 0; if (tag > 8) tag = 8;
            out[(long)b * S_LEN + (s2 - 1)] = (float)tag;
        }
    }
}

// -------------------------------------------------------------------------
extern "C" void kernel_launch(void* const* d_in, const int* in_sizes, int n_in,
                              void* d_out, int out_size, void* d_ws, size_t ws_size,
                              hipStream_t stream) {
    const int* x = (const int*)d_in[0];
    float* out = (float*)d_out;

    fill_out<<<(out_size + 255) / 256, 256, 0, stream>>>(out, out_size);
    convert_kernel<<<512, 256, 0, stream>>>(
        d_in[1], d_in[2], d_in[3], d_in[4], d_in[5], d_in[6],
        d_in[7], d_in[8], d_in[9], d_in[10], d_in[11], d_in[12],
        d_in[13], d_in[14], d_in[15]);
    px_gemm<<<dim3(16, 2, 8), 512, 0, stream>>>(x);
    scan_mfma<<<dim3(16, 2), 1024, 0, stream>>>();
    emission_kernel<<<8192, 256, 0, stream>>>();
    viterbi_kernel<<<64, 256, 0, stream>>>(out, out_size);
}

// Round 3
// 988.884 us; speedup vs baseline: 1.1535x; 1.0049x over previous
//
#include <hip/hip_runtime.h>
#include <hip/hip_bf16.h>
#include <math.h>

#define S_LEN 512
#define B_SZ  256
#define E_DIM 128
#define HHID  128
#define G4    512   // 4*HH
#define T_TAG 9
#define NR    (S_LEN * B_SZ)   // r = s*256 + b
#define VOCAB 5001

typedef __attribute__((ext_vector_type(8))) short bf16x8;
typedef __attribute__((ext_vector_type(4))) float f32x4;

__device__ __forceinline__ float bf2f(__hip_bfloat16 v) { return __bfloat162float(v); }
__device__ __forceinline__ float scrub0(float v) {       // inf/nan -> 0
    unsigned u = __float_as_uint(v);
    return (((u >> 23) & 0xFFu) == 0xFFu) ? 0.f : v;
}
__device__ __forceinline__ float frcp(float x) { return __builtin_amdgcn_rcpf(x); }
__device__ __forceinline__ float fsig(float x) { return frcp(1.f + __expf(-x)); }
__device__ __forceinline__ float ftanh(float x) {
    return 1.f - 2.f * frcp(1.f + __expf(2.f * x));
}

// ---- .bss scratch ----
__device__ __hip_bfloat16 g_emb[VOCAB * E_DIM];
__device__ __hip_bfloat16 g_wih[2][G4 * E_DIM];    // rows permuted: n' = 4u+g
__device__ __hip_bfloat16 g_whh2[2][G4 * HHID];    // rows permuted: n' = 4u+g
__device__ __align__(16) float g_bias[2][G4];      // permuted
__device__ float g_wout[T_TAG * 256];
__device__ float g_bout[T_TAG];
__device__ float g_trans[T_TAG * T_TAG];
__device__ float g_start[T_TAG];
__device__ float g_end[T_TAG];
__device__ float g_maskf[B_SZ * S_LEN];
__device__ float g_em[(long)NR * T_TAG];
__device__ __align__(16) float g_hs[2][(long)NR * HHID];  // [(s*16+bg)*128+u]*16+m
// px = bias + Wih'@emb, precomputed for all steps. Layout:
// [dir][s][bg][u][m16][g] — scan reads 1KB contiguous per wave per tile.
__device__ __align__(16) float g_px[(long)2 * S_LEN * 16 * 128 * 16 * 4];  // 512 MiB

// -------------------------------------------------------------------------
__global__ __launch_bounds__(256) void fill_out(float* out, int n) {
    const int i = blockIdx.x * 256 + threadIdx.x;
    if (i < n) out[i] = 0.f;
}

// -------------------------------------------------------------------------
// Canonicalize inputs (bf16/fp32 autodetect via mask). Gate permutation:
// row n' = 4u+g  <->  original torch gate row g*128+u.
// -------------------------------------------------------------------------
__global__ __launch_bounds__(256) void convert_kernel(
    const void* mask, const void* emb,
    const void* wih_f, const void* whh_f, const void* bih_f, const void* bhh_f,
    const void* wih_b, const void* whh_b, const void* bih_b, const void* bhh_b,
    const void* wout, const void* bout, const void* trans,
    const void* startt, const void* endt)
{
    const bool isb = (((const unsigned*)mask)[0] == 0x3F803F80u);
    auto ldf = [&](const void* p, long i) -> float {
        float v = isb ? bf2f(((const __hip_bfloat16*)p)[i]) : ((const float*)p)[i];
        return scrub0(v);
    };
    const long tid0   = (long)blockIdx.x * blockDim.x + threadIdx.x;
    const long stride = (long)gridDim.x * blockDim.x;

    for (long i = tid0; i < (long)VOCAB * E_DIM; i += stride)
        g_emb[i] = __float2bfloat16(ldf(emb, i));
    for (long i = tid0; i < (long)G4 * E_DIM; i += stride) {
        const int np = (int)(i >> 7), e = (int)(i & 127);
        const int g = np & 3, u = np >> 2;
        const long src = (long)(g * 128 + u) * E_DIM + e;
        g_wih[0][i] = __float2bfloat16(ldf(wih_f, src));
        g_wih[1][i] = __float2bfloat16(ldf(wih_b, src));
    }
    for (long i = tid0; i < (long)G4 * HHID; i += stride) {
        const int np = (int)(i >> 7), k = (int)(i & 127);
        const int g = np & 3, u = np >> 2;
        const long src = (long)(g * 128 + u) * HHID + k;
        g_whh2[0][i] = __float2bfloat16(ldf(whh_f, src));
        g_whh2[1][i] = __float2bfloat16(ldf(whh_b, src));
    }
    for (long i = tid0; i < G4; i += stride) {
        const int g = (int)i & 3, u = (int)i >> 2;
        const long src = g * 128 + u;
        g_bias[0][i] = ldf(bih_f, src) + ldf(bhh_f, src);
        g_bias[1][i] = ldf(bih_b, src) + ldf(bhh_b, src);
    }
    for (long i = tid0; i < T_TAG * 256; i += stride) g_wout[i] = ldf(wout, i);
    for (long i = tid0; i < T_TAG * T_TAG; i += stride) g_trans[i] = ldf(trans, i);
    for (long i = tid0; i < T_TAG; i += stride) {
        g_bout[i]  = ldf(bout, i);
        g_start[i] = ldf(startt, i);
        g_end[i]   = ldf(endt, i);
    }
    for (long i = tid0; i < (long)B_SZ * S_LEN; i += stride)
        g_maskf[i] = ldf(mask, i);
}

// -------------------------------------------------------------------------
// Bulk input projection on ALL CUs: px[dir][s][bg] = bias + Wih'@emb^T,
// bit-exact replication of the in-scan px MFMA sequence. Block = 512
// threads (8 waves, 4 tiles each), grid (16 bg, 2 dir, 8 s-chunks).
// -------------------------------------------------------------------------
__global__ __launch_bounds__(512, 2) void px_gemm(const int* __restrict__ x)
{
    const int bg = blockIdx.x, dir = blockIdx.y, sc = blockIdx.z;
    const int tid  = threadIdx.x;
    const int lane = tid & 63, wv = tid >> 6;
    const int m16  = lane & 15, quad = lane >> 4;

    bf16x8 V[4][4];
    f32x4 bias4[4];
    #pragma unroll
    for (int t = 0; t < 4; t++) {
        const int np = (wv * 4 + t) * 16 + m16;
        #pragma unroll
        for (int kk = 0; kk < 4; kk++)
            V[t][kk] = *(const bf16x8*)&g_wih[dir][(long)np * E_DIM + kk * 32 + quad * 8];
        const int u = 16 * wv + 4 * t + quad;
        const float4 b4 = *(const float4*)&g_bias[dir][4 * u];
        bias4[t] = (f32x4){b4.x, b4.y, b4.z, b4.w};
    }
    const bool x64 = ((x[1] | x[3] | x[5] | x[7]) == 0);
    const int b = bg * 16 + m16;
    const int s0 = sc * 64;
    for (int s = s0; s < s0 + 64; s++) {
        const int ii = b * S_LEN + s;
        const int xo = (x64 ? x[2 * ii] : x[ii]) * E_DIM;
        bf16x8 E[4];
        #pragma unroll
        for (int kk = 0; kk < 4; kk++)
            E[kk] = *(const bf16x8*)&g_emb[(long)xo + kk * 32 + quad * 8];
        #pragma unroll
        for (int t = 0; t < 4; t++) {
            f32x4 px = bias4[t];
            #pragma unroll
            for (int kk = 0; kk < 4; kk++)
                px = __builtin_amdgcn_mfma_f32_16x16x32_bf16(V[t][kk], E[kk], px, 0, 0, 0);
            const int u = 16 * wv + 4 * t + quad;
            const long idx = (((long)(dir * S_LEN + s) * 16 + bg) * 128 + u) * 64 + m16 * 4;
            *(f32x4*)&g_px[idx] = px;
        }
    }
}

// -------------------------------------------------------------------------
// Recurrence-only MFMA scan, 8 waves x 4 gate-tiles per wave.
// Rationale: the h B-operand LDS traffic is (waves x 8KB)/step — 8 waves
// halves it vs 16 (128->64 KB/step, ~1540->~770 cy at 85 B/cy), while
// per-SIMD VALU work is unchanged (8 tiles/SIMD either way).
// px comes from g_px (2-step parity prefetch, rides across the raw barrier).
// Lane (wv,quad,m16) tile t: gates i,f,g,o (reg 0..3) of u=16wv+4t+quad,
// batch m16. ONE lgkm-only barrier/step (vmcnt stays in flight).
// Accumulation order identical to previous rounds — bit-exact numerics.
// -------------------------------------------------------------------------
#define SCAN_STEP(RD, PX)                                                      \
  {                                                                            \
    const int wr_ = (RD) ^ 1;                                                  \
    bf16x8 Hh_[4], Hl_[4];                                                     \
    _Pragma("unroll")                                                          \
    for (int kk = 0; kk < 4; kk++) {                                           \
        const int off_ = ((kk * 4 + quad) * 16 + m16) * 8;                     \
        Hh_[kk] = *(const bf16x8*)&hB[RD][0][off_];                            \
        Hl_[kk] = *(const bf16x8*)&hB[RD][1][off_];                            \
    }                                                                          \
    _Pragma("unroll")                                                          \
    for (int t = 0; t < 4; t++) {                                              \
        _Pragma("unroll")                                                      \
        for (int kk = 0; kk < 4; kk++) {                                       \
            PX[t] = __builtin_amdgcn_mfma_f32_16x16x32_bf16(W[t][kk], Hh_[kk], PX[t], 0, 0, 0); \
            PX[t] = __builtin_amdgcn_mfma_f32_16x16x32_bf16(W[t][kk], Hl_[kk], PX[t], 0, 0, 0); \
        }                                                                      \
    }                                                                          \
    _Pragma("unroll")                                                          \
    for (int t = 0; t < 4; t++) {                                              \
        const float iv = fsig(PX[t][0]);                                       \
        const float fv = fsig(PX[t][1]);                                       \
        const float gv = ftanh(PX[t][2]);                                      \
        const float ov = fsig(PX[t][3]);                                       \
        c[t] = fv * c[t] + iv * gv;                                            \
        const float h = ov * ftanh(c[t]);                                      \
        const int u = 16 * wv + 4 * t + quad;                                  \
        const unsigned ub = __float_as_uint(h);                                \
        const unsigned hb_ = ub >> 16;                                         \
        const float hif = __uint_as_float(ub & 0xFFFF0000u);                   \
        const unsigned lb_ = __float_as_uint(h - hif) >> 16;                   \
        const int ha = (u >> 3) * 128 + m16 * 8 + (u & 7);                     \
        hB[wr_][0][ha] = (unsigned short)hb_;                                  \
        hB[wr_][1][ha] = (unsigned short)lb_;                                  \
        hsp[t * 64] = h;                                                       \
    }                                                                          \
    {   /* reload PX for step itv+2 (parity double-buffer, clamped) */         \
        const float* pf_ = (itv + 2 < S_LEN) ? (pxp + 2 * pxd) : pxp;          \
        PX[0] = *(const f32x4*)(pf_ + 0);                                      \
        PX[1] = *(const f32x4*)(pf_ + 256);                                    \
        PX[2] = *(const f32x4*)(pf_ + 512);                                    \
        PX[3] = *(const f32x4*)(pf_ + 768);                                    \
    }                                                                          \
    asm volatile("s_waitcnt lgkmcnt(0)" ::: "memory");                         \
    __builtin_amdgcn_sched_barrier(0);                                         \
    __builtin_amdgcn_s_barrier();                                              \
    __builtin_amdgcn_sched_barrier(0);                                         \
    hsp += hsd; pxp += pxd; itv++;                                             \
  }

__global__ __launch_bounds__(512, 2) void scan_mfma()
{
    __shared__ __align__(16) unsigned short hB[2][2][16 * 16 * 8];  // 16 KB

    const int bg = blockIdx.x, dir = blockIdx.y;
    const int tid  = threadIdx.x;
    const int lane = tid & 63, wv = tid >> 6;        // wv 0..7
    const int m16  = lane & 15, quad = lane >> 4;

    // persistent A fragments: Whh' rows (4 tiles of 16 rows per wave)
    bf16x8 W[4][4];
    #pragma unroll
    for (int t = 0; t < 4; t++) {
        const int np = (wv * 4 + t) * 16 + m16;
        #pragma unroll
        for (int kk = 0; kk < 4; kk++)
            W[t][kk] = *(const bf16x8*)&g_whh2[dir][(long)np * HHID + kk * 32 + quad * 8];
    }
    for (int i = tid; i < 2 * 2 * 2048; i += 512) ((unsigned short*)hB)[i] = 0;
    float c[4] = {0.f, 0.f, 0.f, 0.f};

    const int se0  = dir ? (S_LEN - 1) : 0;
    const int step = dir ? -1 : 1;
    const int u0   = 16 * wv + quad;

    // px pointers: current-step base + per-step delta (s-stride = 131072 f32)
    const float* pxp = &g_px[(((long)(dir * S_LEN + se0) * 16 + bg) * 128 + u0) * 64 + m16 * 4];
    const long pxd = (long)step * 131072;

    f32x4 pxA[4], pxB[4];
    #pragma unroll
    for (int t = 0; t < 4; t++) pxA[t] = *(const f32x4*)(pxp + t * 256);
    {
        const float* p1 = pxp + pxd;
        #pragma unroll
        for (int t = 0; t < 4; t++) pxB[t] = *(const f32x4*)(p1 + t * 256);
    }

    // incremental hs store base: ((se*16+bg)*128 + u0)*16 + m16, tiles at
    // +0,+64,+128,+192 floats; per-step delta = step*32768 floats
    float* hsp = &g_hs[dir][((long)(se0 * 16 + bg) * 128 + u0) * 16 + m16];
    const long hsd = (long)step * 32768;

    int itv = 0;
    __syncthreads();

    for (int it = 0; it < S_LEN; it += 2) {
        SCAN_STEP(0, pxA)      // even step: read hB[0], write hB[1]
        SCAN_STEP(1, pxB)      // odd step:  read hB[1], write hB[0]
    }
}

// -------------------------------------------------------------------------
// Bulk emission from hs layout: block = (s,bg) tile [128u x 16m], staged in
// LDS; thread (m, j<9) dots 256-k. em[r*9+j] includes bout.
// -------------------------------------------------------------------------
__global__ __launch_bounds__(256, 4) void emission_kernel()
{
    __shared__ float hfL[2048], hbL[2048];
    __shared__ float Wsh[T_TAG][256];
    __shared__ float bo[T_TAG];
    const int tid = threadIdx.x, blk = blockIdx.x;   // 0..8191 = s*16+bg
    for (int i = tid; i < T_TAG * 256; i += 256) Wsh[i >> 8][i & 255] = g_wout[i];
    if (tid < T_TAG) bo[tid] = g_bout[tid];
    const float* hf = &g_hs[0][(long)blk * 2048];
    const float* hb = &g_hs[1][(long)blk * 2048];
    for (int i = tid; i < 2048; i += 256) { hfL[i] = hf[i]; hbL[i] = hb[i]; }
    __syncthreads();

    const int m = tid & 15, j = tid >> 4;
    if (j < T_TAG) {
        float acc = bo[j];
        #pragma unroll 4
        for (int u = 0; u < 128; u++)
            acc += hfL[u * 16 + m] * Wsh[j][u] + hbL[u * 16 + m] * Wsh[j][128 + u];
        const int r = (blk >> 4) * 256 + (blk & 15) * 16 + m;   // s*256 + b
        g_em[(long)r * T_TAG + j] = scrub0(acc);
    }
}

// -------------------------------------------------------------------------
// Viterbi: 1 wave per batch element (lanes 0..8 = tags), score broadcast via
// wave shfl — NO per-step barrier. Strict-> argmax = jnp first-max.
// -------------------------------------------------------------------------
__global__ __launch_bounds__(256, 2)
void viterbi_kernel(float* __restrict__ out, int out_size)
{
    __shared__ unsigned char bp[4][S_LEN][T_TAG];
    const int wid  = threadIdx.x >> 6;
    const int lane = threadIdx.x & 63;
    const int b  = blockIdx.x * 4 + wid;
    const int jj = (lane < T_TAG) ? lane : 0;

    float tcol[T_TAG];
    #pragma unroll
    for (int i = 0; i < T_TAG; i++) tcol[i] = g_trans[i * T_TAG + jj];

    float score[T_TAG];
    {
        const float m0 = g_maskf[b * S_LEN + 0];
        #pragma unroll
        for (int i = 0; i < T_TAG; i++)
            score[i] = g_start[i] + g_em[(long)b * T_TAG + i] * m0;
    }
    float e = g_em[((long)1 * B_SZ + b) * T_TAG + jj];
    float m = g_maskf[b * S_LEN + 1];

    for (int s = 1; s < S_LEN; s++) {
        float en = 0.f, mn = 0.f;
        if (s + 1 < S_LEN) {   // prefetch next step
            en = g_em[((long)(s + 1) * B_SZ + b) * T_TAG + jj];
            mn = g_maskf[b * S_LEN + s + 1];
        }
        float best = score[0] + tcol[0];
        int arg = 0;
        #pragma unroll
        for (int i = 1; i < T_TAG; i++) {
            const float cnd = score[i] + tcol[i];
            if (cnd > best) { best = cnd; arg = i; }
        }
        float ns; int nbp;
        if (m > 0.f) { ns = best + e * m; nbp = arg; }
        else         { ns = score[jj];    nbp = jj;  }
        if (lane < T_TAG) bp[wid][s][jj] = (unsigned char)nbp;
        #pragma unroll
        for (int i = 0; i < T_TAG; i++) score[i] = __shfl(ns, i, 64);
        e = en; m = mn;
    }
    #pragma unroll
    for (int i = 0; i < T_TAG; i++) score[i] += g_end[i];

    __syncthreads();   // bp visible for backtrace

    if (lane == 0) {
        float bs = score[0]; int last = 0;
        #pragma unroll
        for (int i = 1; i < T_TAG; i++)
            if (score[i] > bs) { bs = score[i]; last = i; }
        {
            const unsigned u = __float_as_uint(bs);
            if (((u >> 23) & 0xFFu) == 0xFFu) bs = -100.f;
        }
        if ((long)B_SZ * S_LEN + b < out_size)
            out[(long)B_SZ * S_LEN + b] = bs;
        int tag = last;
        if (tag < 0) tag = 0; if (tag > 8) tag = 8;
        out[(long)b * S_LEN + (S_LEN - 1)] = (float)tag;
        for (int s2 = S_LEN - 1; s2 >= 1; s2--) {
            tag = bp[wid][s2][tag];
            if (tag < 0) tag = 0; if (tag > 8) tag = 8;
            out[(long)b * S_LEN + (s2 - 1)] = (float)tag;
        }
    }
}

// -------------------------------------------------------------------------
extern "C" void kernel_launch(void* const* d_in, const int* in_sizes, int n_in,
                              void* d_out, int out_size, void* d_ws, size_t ws_size,
                              hipStream_t stream) {
    const int* x = (const int*)d_in[0];
    float* out = (float*)d_out;

    fill_out<<<(out_size + 255) / 256, 256, 0, stream>>>(out, out_size);
    convert_kernel<<<512, 256, 0, stream>>>(
        d_in[1], d_in[2], d_in[3], d_in[4], d_in[5], d_in[6],
        d_in[7], d_in[8], d_in[9], d_in[10], d_in[11], d_in[12],
        d_in[13], d_in[14], d_in[15]);
    px_gemm<<<dim3(16, 2, 8), 512, 0, stream>>>(x);
    scan_mfma<<<dim3(16, 2), 512, 0, stream>>>();
    emission_kernel<<<8192, 256, 0, stream>>>();
    viterbi_kernel<<<64, 256, 0, stream>>>(out, out_size);
}

// Round 4
// 938.311 us; speedup vs baseline: 1.2157x; 1.0539x over previous
//
#include <hip/hip_runtime.h>
#include <hip/hip_bf16.h>
#include <math.h>

#define S_LEN 512
#define B_SZ  256
#define E_DIM 128
#define HHID  128
#define G4    512   // 4*HH
#define T_TAG 9
#define NR    (S_LEN * B_SZ)   // r = s*256 + b
#define VOCAB 5001
#define VOCABP 5008   // padded to 16 for pxv tiling

typedef __attribute__((ext_vector_type(8))) short bf16x8;
typedef __attribute__((ext_vector_type(4))) float f32x4;

__device__ __forceinline__ float bf2f(__hip_bfloat16 v) { return __bfloat162float(v); }
__device__ __forceinline__ float scrub0(float v) {       // inf/nan -> 0
    unsigned u = __float_as_uint(v);
    return (((u >> 23) & 0xFFu) == 0xFFu) ? 0.f : v;
}
__device__ __forceinline__ float frcp(float x) { return __builtin_amdgcn_rcpf(x); }
__device__ __forceinline__ float fsig(float x) { return frcp(1.f + __expf(-x)); }
__device__ __forceinline__ float ftanh(float x) {
    return 1.f - 2.f * frcp(1.f + __expf(2.f * x));
}

// ---- .bss scratch ----
__device__ __hip_bfloat16 g_emb[VOCAB * E_DIM];
__device__ __hip_bfloat16 g_wih[2][G4 * E_DIM];    // rows permuted: n' = 4u+g
__device__ __hip_bfloat16 g_whh2[2][G4 * HHID];    // rows permuted: n' = 4u+g
__device__ __align__(16) float g_bias[2][G4];      // permuted
__device__ float g_wout[T_TAG * 256];
__device__ float g_bout[T_TAG];
__device__ float g_trans[T_TAG * T_TAG];
__device__ float g_start[T_TAG];
__device__ float g_end[T_TAG];
__device__ float g_maskf[B_SZ * S_LEN];
__device__ float g_em[(long)NR * T_TAG];
__device__ __align__(16) float g_hs[2][(long)NR * HHID];  // [(s*16+bg)*128+u]*16+m
// pxv[dir][v][u][g] = bias + Wih'@emb[v] for every VOCAB token (20.5 MB,
// L2/L3-resident). Scan gathers by token id — replaces the 512 MiB px stream.
__device__ __align__(16) float g_pxv[(long)2 * VOCABP * 128 * 4];

// -------------------------------------------------------------------------
__global__ __launch_bounds__(256) void fill_out(float* out, int n) {
    const int i = blockIdx.x * 256 + threadIdx.x;
    if (i < n) out[i] = 0.f;
}

// -------------------------------------------------------------------------
// Canonicalize inputs (bf16/fp32 autodetect via mask). Gate permutation:
// row n' = 4u+g  <->  original torch gate row g*128+u.
// -------------------------------------------------------------------------
__global__ __launch_bounds__(256) void convert_kernel(
    const void* mask, const void* emb,
    const void* wih_f, const void* whh_f, const void* bih_f, const void* bhh_f,
    const void* wih_b, const void* whh_b, const void* bih_b, const void* bhh_b,
    const void* wout, const void* bout, const void* trans,
    const void* startt, const void* endt)
{
    const bool isb = (((const unsigned*)mask)[0] == 0x3F803F80u);
    auto ldf = [&](const void* p, long i) -> float {
        float v = isb ? bf2f(((const __hip_bfloat16*)p)[i]) : ((const float*)p)[i];
        return scrub0(v);
    };
    const long tid0   = (long)blockIdx.x * blockDim.x + threadIdx.x;
    const long stride = (long)gridDim.x * blockDim.x;

    for (long i = tid0; i < (long)VOCAB * E_DIM; i += stride)
        g_emb[i] = __float2bfloat16(ldf(emb, i));
    for (long i = tid0; i < (long)G4 * E_DIM; i += stride) {
        const int np = (int)(i >> 7), e = (int)(i & 127);
        const int g = np & 3, u = np >> 2;
        const long src = (long)(g * 128 + u) * E_DIM + e;
        g_wih[0][i] = __float2bfloat16(ldf(wih_f, src));
        g_wih[1][i] = __float2bfloat16(ldf(wih_b, src));
    }
    for (long i = tid0; i < (long)G4 * HHID; i += stride) {
        const int np = (int)(i >> 7), k = (int)(i & 127);
        const int g = np & 3, u = np >> 2;
        const long src = (long)(g * 128 + u) * HHID + k;
        g_whh2[0][i] = __float2bfloat16(ldf(whh_f, src));
        g_whh2[1][i] = __float2bfloat16(ldf(whh_b, src));
    }
    for (long i = tid0; i < G4; i += stride) {
        const int g = (int)i & 3, u = (int)i >> 2;
        const long src = g * 128 + u;
        g_bias[0][i] = ldf(bih_f, src) + ldf(bhh_f, src);
        g_bias[1][i] = ldf(bih_b, src) + ldf(bhh_b, src);
    }
    for (long i = tid0; i < T_TAG * 256; i += stride) g_wout[i] = ldf(wout, i);
    for (long i = tid0; i < T_TAG * T_TAG; i += stride) g_trans[i] = ldf(trans, i);
    for (long i = tid0; i < T_TAG; i += stride) {
        g_bout[i]  = ldf(bout, i);
        g_start[i] = ldf(startt, i);
        g_end[i]   = ldf(endt, i);
    }
    for (long i = tid0; i < (long)B_SZ * S_LEN; i += stride)
        g_maskf[i] = ldf(mask, i);
}

// -------------------------------------------------------------------------
// Per-VOCAB input projection: pxv[dir][v] = bias + Wih'@emb[v]^T. MFMA
// columns = 16 tokens per block. Bit-exact same fragments/accumulation order
// as the old per-(s,b) px compute — gathering by token reproduces px exactly.
// Grid (313 token-groups, 2 dir), 512 threads (8 waves x 4 tiles).
// -------------------------------------------------------------------------
__global__ __launch_bounds__(512, 2) void pxv_gemm()
{
    const int grp = blockIdx.x, dir = blockIdx.y;
    const int tid  = threadIdx.x;
    const int lane = tid & 63, wv = tid >> 6;
    const int m16  = lane & 15, quad = lane >> 4;

    bf16x8 V[4][4];
    f32x4 bias4[4];
    #pragma unroll
    for (int t = 0; t < 4; t++) {
        const int np = (wv * 4 + t) * 16 + m16;
        #pragma unroll
        for (int kk = 0; kk < 4; kk++)
            V[t][kk] = *(const bf16x8*)&g_wih[dir][(long)np * E_DIM + kk * 32 + quad * 8];
        const int u = 16 * wv + 4 * t + quad;
        const float4 b4 = *(const float4*)&g_bias[dir][4 * u];
        bias4[t] = (f32x4){b4.x, b4.y, b4.z, b4.w};
    }
    const int v  = grp * 16 + m16;
    const int vv = (v < VOCAB) ? v : 0;
    bf16x8 E[4];
    #pragma unroll
    for (int kk = 0; kk < 4; kk++)
        E[kk] = *(const bf16x8*)&g_emb[(long)vv * E_DIM + kk * 32 + quad * 8];
    #pragma unroll
    for (int t = 0; t < 4; t++) {
        f32x4 px = bias4[t];
        #pragma unroll
        for (int kk = 0; kk < 4; kk++)
            px = __builtin_amdgcn_mfma_f32_16x16x32_bf16(V[t][kk], E[kk], px, 0, 0, 0);
        const int u = 16 * wv + 4 * t + quad;
        if (v < VOCAB)
            *(f32x4*)&g_pxv[((long)(dir * VOCABP + v) * 128 + u) * 4] = px;
    }
}

// -------------------------------------------------------------------------
// Recurrence-only MFMA scan, 8 waves x 4 gate-tiles per wave.
// px is GATHERED from the 20.5 MB cache-resident g_pxv by token id (xO LDS
// table, 2-step parity prefetch riding across the raw lgkm-only barrier).
// Lane (wv,quad,m16) tile t: gates i,f,g,o (reg 0..3) of u=16wv+4t+quad,
// batch m16. ONE lgkm-only barrier/step (vmcnt stays in flight).
// Accumulation order identical to previous rounds — bit-exact numerics.
// -------------------------------------------------------------------------
#define SCAN_STEP(RD, PX)                                                      \
  {                                                                            \
    const int wr_ = (RD) ^ 1;                                                  \
    bf16x8 Hh_[4], Hl_[4];                                                     \
    _Pragma("unroll")                                                          \
    for (int kk = 0; kk < 4; kk++) {                                           \
        const int off_ = ((kk * 4 + quad) * 16 + m16) * 8;                     \
        Hh_[kk] = *(const bf16x8*)&hB[RD][0][off_];                            \
        Hl_[kk] = *(const bf16x8*)&hB[RD][1][off_];                            \
    }                                                                          \
    _Pragma("unroll")                                                          \
    for (int t = 0; t < 4; t++) {                                              \
        _Pragma("unroll")                                                      \
        for (int kk = 0; kk < 4; kk++) {                                       \
            PX[t] = __builtin_amdgcn_mfma_f32_16x16x32_bf16(W[t][kk], Hh_[kk], PX[t], 0, 0, 0); \
            PX[t] = __builtin_amdgcn_mfma_f32_16x16x32_bf16(W[t][kk], Hl_[kk], PX[t], 0, 0, 0); \
        }                                                                      \
    }                                                                          \
    _Pragma("unroll")                                                          \
    for (int t = 0; t < 4; t++) {                                              \
        const float iv = fsig(PX[t][0]);                                       \
        const float fv = fsig(PX[t][1]);                                       \
        const float gv = ftanh(PX[t][2]);                                      \
        const float ov = fsig(PX[t][3]);                                       \
        c[t] = fv * c[t] + iv * gv;                                            \
        const float h = ov * ftanh(c[t]);                                      \
        const int u = 16 * wv + 4 * t + quad;                                  \
        const unsigned ub = __float_as_uint(h);                                \
        const unsigned hb_ = ub >> 16;                                         \
        const float hif = __uint_as_float(ub & 0xFFFF0000u);                   \
        const unsigned lb_ = __float_as_uint(h - hif) >> 16;                   \
        const int ha = (u >> 3) * 128 + m16 * 8 + (u & 7);                     \
        hB[wr_][0][ha] = (unsigned short)hb_;                                  \
        hB[wr_][1][ha] = (unsigned short)lb_;                                  \
        hsp[t * 64] = h;                                                       \
    }                                                                          \
    {   /* gather PX for step itv+2 (parity double-buffer, clamped addr) */    \
        int se2 = sev + 2 * step;                                              \
        se2 = se2 < 0 ? 0 : (se2 > S_LEN - 1 ? S_LEN - 1 : se2);               \
        const int off2 = xO[se2 * 16 + m16];                                   \
        const float* pf_ = pxvL + off2;                                        \
        PX[0] = *(const f32x4*)(pf_ + 0);                                      \
        PX[1] = *(const f32x4*)(pf_ + 16);                                     \
        PX[2] = *(const f32x4*)(pf_ + 32);                                     \
        PX[3] = *(const f32x4*)(pf_ + 48);                                     \
    }                                                                          \
    asm volatile("s_waitcnt lgkmcnt(0)" ::: "memory");                         \
    __builtin_amdgcn_sched_barrier(0);                                         \
    __builtin_amdgcn_s_barrier();                                              \
    __builtin_amdgcn_sched_barrier(0);                                         \
    hsp += hsd; sev += step; itv++;                                            \
  }

__global__ __launch_bounds__(512, 2) void scan_mfma(const int* __restrict__ x)
{
    __shared__ __align__(16) unsigned short hB[2][2][16 * 16 * 8];  // 16 KB
    __shared__ int xO[S_LEN * 16];   // token * 512 (pxv element offset), 32 KB

    const int bg = blockIdx.x, dir = blockIdx.y;
    const int tid  = threadIdx.x;
    const int lane = tid & 63, wv = tid >> 6;        // wv 0..7
    const int m16  = lane & 15, quad = lane >> 4;

    // persistent A fragments: Whh' rows (4 tiles of 16 rows per wave)
    bf16x8 W[4][4];
    #pragma unroll
    for (int t = 0; t < 4; t++) {
        const int np = (wv * 4 + t) * 16 + m16;
        #pragma unroll
        for (int kk = 0; kk < 4; kk++)
            W[t][kk] = *(const bf16x8*)&g_whh2[dir][(long)np * HHID + kk * 32 + quad * 8];
    }
    {   // stage token offsets: xO[s*16+m] = x[bg*16+m][s] * 512
        const bool x64 = ((x[1] | x[3] | x[5] | x[7]) == 0);
        for (int i = tid; i < S_LEN * 16; i += 512) {
            const int s = i >> 4, m = i & 15;
            const int ii = (bg * 16 + m) * S_LEN + s;
            int tok = x64 ? x[2 * ii] : x[ii];
            tok = (unsigned)tok < VOCAB ? tok : 0;
            xO[i] = tok * 512;
        }
    }
    for (int i = tid; i < 2 * 2 * 2048; i += 512) ((unsigned short*)hB)[i] = 0;
    float c[4] = {0.f, 0.f, 0.f, 0.f};
    __syncthreads();

    const int se0  = dir ? (S_LEN - 1) : 0;
    const int step = dir ? -1 : 1;
    const int u0   = 16 * wv + quad;

    // pxv lane base: element ((dir*VOCABP + v)*128 + u)*4; v enters via xO
    const float* pxvL = &g_pxv[(long)dir * VOCABP * 512 + u0 * 4];

    f32x4 pxA[4], pxB[4];
    {
        const int o0 = xO[se0 * 16 + m16];
        #pragma unroll
        for (int t = 0; t < 4; t++) pxA[t] = *(const f32x4*)(pxvL + o0 + 16 * t);
        const int se1 = (S_LEN > 1) ? se0 + step : se0;
        const int o1 = xO[se1 * 16 + m16];
        #pragma unroll
        for (int t = 0; t < 4; t++) pxB[t] = *(const f32x4*)(pxvL + o1 + 16 * t);
    }

    // incremental hs store base: ((se*16+bg)*128 + u0)*16 + m16, tiles at
    // +0,+64,+128,+192 floats; per-step delta = step*32768 floats
    float* hsp = &g_hs[dir][((long)(se0 * 16 + bg) * 128 + u0) * 16 + m16];
    const long hsd = (long)step * 32768;

    int itv = 0, sev = se0;

    for (int it = 0; it < S_LEN; it += 2) {
        SCAN_STEP(0, pxA)      // even step: read hB[0], write hB[1]
        SCAN_STEP(1, pxB)      // odd step:  read hB[1], write hB[0]
    }
}

// -------------------------------------------------------------------------
// Bulk emission from hs layout: block = (s,bg) tile [128u x 16m], staged in
// LDS; thread (m, j<9) dots 256-k. em[r*9+j] includes bout.
// -------------------------------------------------------------------------
__global__ __launch_bounds__(256, 4) void emission_kernel()
{
    __shared__ float hfL[2048], hbL[2048];
    __shared__ float Wsh[T_TAG][256];
    __shared__ float bo[T_TAG];
    const int tid = threadIdx.x, blk = blockIdx.x;   // 0..8191 = s*16+bg
    for (int i = tid; i < T_TAG * 256; i += 256) Wsh[i >> 8][i & 255] = g_wout[i];
    if (tid < T_TAG) bo[tid] = g_bout[tid];
    const float* hf = &g_hs[0][(long)blk * 2048];
    const float* hb = &g_hs[1][(long)blk * 2048];
    for (int i = tid; i < 2048; i += 256) { hfL[i] = hf[i]; hbL[i] = hb[i]; }
    __syncthreads();

    const int m = tid & 15, j = tid >> 4;
    if (j < T_TAG) {
        float acc = bo[j];
        #pragma unroll 4
        for (int u = 0; u < 128; u++)
            acc += hfL[u * 16 + m] * Wsh[j][u] + hbL[u * 16 + m] * Wsh[j][128 + u];
        const int r = (blk >> 4) * 256 + (blk & 15) * 16 + m;   // s*256 + b
        g_em[(long)r * T_TAG + j] = scrub0(acc);
    }
}

// -------------------------------------------------------------------------
// Viterbi: 1 wave per batch element (lanes 0..8 = tags), score broadcast via
// wave shfl — NO per-step barrier. Strict-> argmax = jnp first-max.
// -------------------------------------------------------------------------
__global__ __launch_bounds__(256, 2)
void viterbi_kernel(float* __restrict__ out, int out_size)
{
    __shared__ unsigned char bp[4][S_LEN][T_TAG];
    const int wid  = threadIdx.x >> 6;
    const int lane = threadIdx.x & 63;
    const int b  = blockIdx.x * 4 + wid;
    const int jj = (lane < T_TAG) ? lane : 0;

    float tcol[T_TAG];
    #pragma unroll
    for (int i = 0; i < T_TAG; i++) tcol[i] = g_trans[i * T_TAG + jj];

    float score[T_TAG];
    {
        const float m0 = g_maskf[b * S_LEN + 0];
        #pragma unroll
        for (int i = 0; i < T_TAG; i++)
            score[i] = g_start[i] + g_em[(long)b * T_TAG + i] * m0;
    }
    float e = g_em[((long)1 * B_SZ + b) * T_TAG + jj];
    float m = g_maskf[b * S_LEN + 1];

    for (int s = 1; s < S_LEN; s++) {
        float en = 0.f, mn = 0.f;
        if (s + 1 < S_LEN) {   // prefetch next step
            en = g_em[((long)(s + 1) * B_SZ + b) * T_TAG + jj];
            mn = g_maskf[b * S_LEN + s + 1];
        }
        float best = score[0] + tcol[0];
        int arg = 0;
        #pragma unroll
        for (int i = 1; i < T_TAG; i++) {
            const float cnd = score[i] + tcol[i];
            if (cnd > best) { best = cnd; arg = i; }
        }
        float ns; int nbp;
        if (m > 0.f) { ns = best + e * m; nbp = arg; }
        else         { ns = score[jj];    nbp = jj;  }
        if (lane < T_TAG) bp[wid][s][jj] = (unsigned char)nbp;
        #pragma unroll
        for (int i = 0; i < T_TAG; i++) score[i] = __shfl(ns, i, 64);
        e = en; m = mn;
    }
    #pragma unroll
    for (int i = 0; i < T_TAG; i++) score[i] += g_end[i];

    __syncthreads();   // bp visible for backtrace

    if (lane == 0) {
        float bs = score[0]; int last = 0;
        #pragma unroll
        for (int i = 1; i < T_TAG; i++)
            if (score[i] > bs) { bs = score[i]; last = i; }
        {
            const unsigned u = __float_as_uint(bs);
            if (((u >> 23) & 0xFFu) == 0xFFu) bs = -100.f;
        }
        if ((long)B_SZ * S_LEN + b < out_size)
            out[(long)B_SZ * S_LEN + b] = bs;
        int tag = last;
        if (tag < 0) tag = 0; if (tag > 8) tag = 8;
        out[(long)b * S_LEN + (S_LEN - 1)] = (float)tag;
        for (int s2 = S_LEN - 1; s2 >= 1; s2--) {
            tag = bp[wid][s2][tag];
            if (tag < 0) tag = 0; if (tag > 8) tag = 8;
            out[(long)b * S_LEN + (s2 - 1)] = (float)tag;
        }
    }
}

// -------------------------------------------------------------------------
extern "C" void kernel_launch(void* const* d_in, const int* in_sizes, int n_in,
                              void* d_out, int out_size, void* d_ws, size_t ws_size,
                              hipStream_t stream) {
    const int* x = (const int*)d_in[0];
    float* out = (float*)d_out;

    fill_out<<<(out_size + 255) / 256, 256, 0, stream>>>(out, out_size);
    convert_kernel<<<512, 256, 0, stream>>>(
        d_in[1], d_in[2], d_in[3], d_in[4], d_in[5], d_in[6],
        d_in[7], d_in[8], d_in[9], d_in[10], d_in[11], d_in[12],
        d_in[13], d_in[14], d_in[15]);
    pxv_gemm<<<dim3((VOCABP / 16), 2), 512, 0, stream>>>();
    scan_mfma<<<dim3(16, 2), 512, 0, stream>>>(x);
    emission_kernel<<<8192, 256, 0, stream>>>();
    viterbi_kernel<<<64, 256, 0, stream>>>(out, out_size);
}

// Round 5
// 928.685 us; speedup vs baseline: 1.2283x; 1.0104x over previous
//
#include <hip/hip_runtime.h>
#include <hip/hip_bf16.h>
#include <math.h>

#define S_LEN 512
#define B_SZ  256
#define E_DIM 128
#define HHID  128
#define G4    512   // 4*HH
#define T_TAG 9
#define NR    (S_LEN * B_SZ)   // r = s*256 + b
#define VOCAB 5001
#define VOCABP 5008   // padded to 16 for pxv tiling

typedef __attribute__((ext_vector_type(8))) short bf16x8;
typedef __attribute__((ext_vector_type(4))) float f32x4;

__device__ __forceinline__ float bf2f(__hip_bfloat16 v) { return __bfloat162float(v); }
__device__ __forceinline__ float scrub0(float v) {       // inf/nan -> 0
    unsigned u = __float_as_uint(v);
    return (((u >> 23) & 0xFFu) == 0xFFu) ? 0.f : v;
}
__device__ __forceinline__ float frcp(float x) { return __builtin_amdgcn_rcpf(x); }
__device__ __forceinline__ float fsig(float x) { return frcp(1.f + __expf(-x)); }
__device__ __forceinline__ float ftanh(float x) {
    return 1.f - 2.f * frcp(1.f + __expf(2.f * x));
}

// ---- .bss scratch ----
__device__ __hip_bfloat16 g_emb[VOCAB * E_DIM];
__device__ __hip_bfloat16 g_wih[2][G4 * E_DIM];    // rows permuted: n' = 4u+g
__device__ __hip_bfloat16 g_whh2[2][G4 * HHID];    // rows permuted: n' = 4u+g
__device__ __align__(16) float g_bias[2][G4];      // permuted
__device__ float g_wout[T_TAG * 256];
__device__ float g_bout[T_TAG];
__device__ float g_trans[T_TAG * T_TAG];
__device__ float g_start[T_TAG];
__device__ float g_end[T_TAG];
__device__ float g_maskf[B_SZ * S_LEN];
__device__ float g_em[(long)NR * T_TAG];
__device__ __align__(16) float g_hs[2][(long)NR * HHID];  // [(s*16+bg)*128+u]*16+m
// pxv[dir][v][u][g] = bias + Wih'@emb[v] for every VOCAB token (20.5 MB,
// L2/L3-resident). Scan gathers by token id — replaces the 512 MiB px stream.
__device__ __align__(16) float g_pxv[(long)2 * VOCABP * 128 * 4];

// -------------------------------------------------------------------------
// Canonicalize inputs (bf16/fp32 autodetect via mask). Gate permutation:
// row n' = 4u+g  <->  original torch gate row g*128+u.
// Also zero-fills the output buffer (folded fill_out — one fewer launch).
// -------------------------------------------------------------------------
__global__ __launch_bounds__(256) void convert_kernel(
    const void* mask, const void* emb,
    const void* wih_f, const void* whh_f, const void* bih_f, const void* bhh_f,
    const void* wih_b, const void* whh_b, const void* bih_b, const void* bhh_b,
    const void* wout, const void* bout, const void* trans,
    const void* startt, const void* endt, float* out, int out_size)
{
    const bool isb = (((const unsigned*)mask)[0] == 0x3F803F80u);
    auto ldf = [&](const void* p, long i) -> float {
        float v = isb ? bf2f(((const __hip_bfloat16*)p)[i]) : ((const float*)p)[i];
        return scrub0(v);
    };
    const long tid0   = (long)blockIdx.x * blockDim.x + threadIdx.x;
    const long stride = (long)gridDim.x * blockDim.x;

    for (long i = tid0; i < out_size; i += stride) out[i] = 0.f;
    for (long i = tid0; i < (long)VOCAB * E_DIM; i += stride)
        g_emb[i] = __float2bfloat16(ldf(emb, i));
    for (long i = tid0; i < (long)G4 * E_DIM; i += stride) {
        const int np = (int)(i >> 7), e = (int)(i & 127);
        const int g = np & 3, u = np >> 2;
        const long src = (long)(g * 128 + u) * E_DIM + e;
        g_wih[0][i] = __float2bfloat16(ldf(wih_f, src));
        g_wih[1][i] = __float2bfloat16(ldf(wih_b, src));
    }
    for (long i = tid0; i < (long)G4 * HHID; i += stride) {
        const int np = (int)(i >> 7), k = (int)(i & 127);
        const int g = np & 3, u = np >> 2;
        const long src = (long)(g * 128 + u) * HHID + k;
        g_whh2[0][i] = __float2bfloat16(ldf(whh_f, src));
        g_whh2[1][i] = __float2bfloat16(ldf(whh_b, src));
    }
    for (long i = tid0; i < G4; i += stride) {
        const int g = (int)i & 3, u = (int)i >> 2;
        const long src = g * 128 + u;
        g_bias[0][i] = ldf(bih_f, src) + ldf(bhh_f, src);
        g_bias[1][i] = ldf(bih_b, src) + ldf(bhh_b, src);
    }
    for (long i = tid0; i < T_TAG * 256; i += stride) g_wout[i] = ldf(wout, i);
    for (long i = tid0; i < T_TAG * T_TAG; i += stride) g_trans[i] = ldf(trans, i);
    for (long i = tid0; i < T_TAG; i += stride) {
        g_bout[i]  = ldf(bout, i);
        g_start[i] = ldf(startt, i);
        g_end[i]   = ldf(endt, i);
    }
    for (long i = tid0; i < (long)B_SZ * S_LEN; i += stride)
        g_maskf[i] = ldf(mask, i);
}

// -------------------------------------------------------------------------
// Per-VOCAB input projection: pxv[dir][v] = bias + Wih'@emb[v]^T. MFMA
// columns = 16 tokens per block. Bit-exact same fragments/accumulation order
// as the old per-(s,b) px compute — gathering by token reproduces px exactly.
// Grid (313 token-groups, 2 dir), 512 threads (8 waves x 4 tiles).
// -------------------------------------------------------------------------
__global__ __launch_bounds__(512, 2) void pxv_gemm()
{
    const int grp = blockIdx.x, dir = blockIdx.y;
    const int tid  = threadIdx.x;
    const int lane = tid & 63, wv = tid >> 6;
    const int m16  = lane & 15, quad = lane >> 4;

    bf16x8 V[4][4];
    f32x4 bias4[4];
    #pragma unroll
    for (int t = 0; t < 4; t++) {
        const int np = (wv * 4 + t) * 16 + m16;
        #pragma unroll
        for (int kk = 0; kk < 4; kk++)
            V[t][kk] = *(const bf16x8*)&g_wih[dir][(long)np * E_DIM + kk * 32 + quad * 8];
        const int u = 16 * wv + 4 * t + quad;
        const float4 b4 = *(const float4*)&g_bias[dir][4 * u];
        bias4[t] = (f32x4){b4.x, b4.y, b4.z, b4.w};
    }
    const int v  = grp * 16 + m16;
    const int vv = (v < VOCAB) ? v : 0;
    bf16x8 E[4];
    #pragma unroll
    for (int kk = 0; kk < 4; kk++)
        E[kk] = *(const bf16x8*)&g_emb[(long)vv * E_DIM + kk * 32 + quad * 8];
    #pragma unroll
    for (int t = 0; t < 4; t++) {
        f32x4 px = bias4[t];
        #pragma unroll
        for (int kk = 0; kk < 4; kk++)
            px = __builtin_amdgcn_mfma_f32_16x16x32_bf16(V[t][kk], E[kk], px, 0, 0, 0);
        const int u = 16 * wv + 4 * t + quad;
        if (v < VOCAB)
            *(f32x4*)&g_pxv[((long)(dir * VOCABP + v) * 128 + u) * 4] = px;
    }
}

// -------------------------------------------------------------------------
// Recurrence-only MFMA scan, 8 waves x 4 gate-tiles per wave.
// px is GATHERED from the 20.5 MB cache-resident g_pxv by token id.
// KEY scheduling point (R5): the xO ds_read + gather ADDRESS are computed at
// the TOP of the step, issued ahead of the hB ds_reads — LDS ops complete in
// order, so the compiler's lgkm wait before the first MFMA covers it, hiding
// its ~120cy latency under the MFMA chain. At the gather point only the 4
// global loads remain, and the terminal lgkmcnt(0) waits nothing new.
// (R4 had the xO read late -> ~200 cy/step of exposed LDS latency.)
// Accumulation order identical to previous rounds — bit-exact numerics.
// -------------------------------------------------------------------------
#define SCAN_STEP(RD, PX)                                                      \
  {                                                                            \
    const int wr_ = (RD) ^ 1;                                                  \
    /* early: offset+address for the step+2 gather (latency hides below) */    \
    int se2_ = sev + 2 * step;                                                 \
    se2_ = se2_ < 0 ? 0 : (se2_ > S_LEN - 1 ? S_LEN - 1 : se2_);               \
    const float* pf_ = pxvL + xO[se2_ * 16 + m16];                             \
    bf16x8 Hh_[4], Hl_[4];                                                     \
    _Pragma("unroll")                                                          \
    for (int kk = 0; kk < 4; kk++) {                                           \
        const int off_ = ((kk * 4 + quad) * 16 + m16) * 8;                     \
        Hh_[kk] = *(const bf16x8*)&hB[RD][0][off_];                            \
        Hl_[kk] = *(const bf16x8*)&hB[RD][1][off_];                            \
    }                                                                          \
    _Pragma("unroll")                                                          \
    for (int t = 0; t < 4; t++) {                                              \
        _Pragma("unroll")                                                      \
        for (int kk = 0; kk < 4; kk++) {                                       \
            PX[t] = __builtin_amdgcn_mfma_f32_16x16x32_bf16(W[t][kk], Hh_[kk], PX[t], 0, 0, 0); \
            PX[t] = __builtin_amdgcn_mfma_f32_16x16x32_bf16(W[t][kk], Hl_[kk], PX[t], 0, 0, 0); \
        }                                                                      \
    }                                                                          \
    _Pragma("unroll")                                                          \
    for (int t = 0; t < 4; t++) {                                              \
        const float iv = fsig(PX[t][0]);                                       \
        const float fv = fsig(PX[t][1]);                                       \
        const float gv = ftanh(PX[t][2]);                                      \
        const float ov = fsig(PX[t][3]);                                       \
        c[t] = fv * c[t] + iv * gv;                                            \
        const float h = ov * ftanh(c[t]);                                      \
        const int u = 16 * wv + 4 * t + quad;                                  \
        const unsigned ub = __float_as_uint(h);                                \
        const unsigned hb_ = ub >> 16;                                         \
        const float hif = __uint_as_float(ub & 0xFFFF0000u);                   \
        const unsigned lb_ = __float_as_uint(h - hif) >> 16;                   \
        const int ha = (u >> 3) * 128 + m16 * 8 + (u & 7);                     \
        hB[wr_][0][ha] = (unsigned short)hb_;                                  \
        hB[wr_][1][ha] = (unsigned short)lb_;                                  \
        hsp[t * 64] = h;                                                       \
    }                                                                          \
    {   /* gather PX for step itv+2 — address precomputed at step top */       \
        PX[0] = *(const f32x4*)(pf_ + 0);                                      \
        PX[1] = *(const f32x4*)(pf_ + 16);                                     \
        PX[2] = *(const f32x4*)(pf_ + 32);                                     \
        PX[3] = *(const f32x4*)(pf_ + 48);                                     \
    }                                                                          \
    asm volatile("s_waitcnt lgkmcnt(0)" ::: "memory");                         \
    __builtin_amdgcn_sched_barrier(0);                                         \
    __builtin_amdgcn_s_barrier();                                              \
    __builtin_amdgcn_sched_barrier(0);                                         \
    hsp += hsd; sev += step; itv++;                                            \
  }

__global__ __launch_bounds__(512, 2) void scan_mfma(const int* __restrict__ x)
{
    __shared__ __align__(16) unsigned short hB[2][2][16 * 16 * 8];  // 16 KB
    __shared__ int xO[S_LEN * 16];   // token * 512 (pxv element offset), 32 KB

    const int bg = blockIdx.x, dir = blockIdx.y;
    const int tid  = threadIdx.x;
    const int lane = tid & 63, wv = tid >> 6;        // wv 0..7
    const int m16  = lane & 15, quad = lane >> 4;

    // persistent A fragments: Whh' rows (4 tiles of 16 rows per wave)
    bf16x8 W[4][4];
    #pragma unroll
    for (int t = 0; t < 4; t++) {
        const int np = (wv * 4 + t) * 16 + m16;
        #pragma unroll
        for (int kk = 0; kk < 4; kk++)
            W[t][kk] = *(const bf16x8*)&g_whh2[dir][(long)np * HHID + kk * 32 + quad * 8];
    }
    {   // stage token offsets: xO[s*16+m] = x[bg*16+m][s] * 512
        const bool x64 = ((x[1] | x[3] | x[5] | x[7]) == 0);
        for (int i = tid; i < S_LEN * 16; i += 512) {
            const int s = i >> 4, m = i & 15;
            const int ii = (bg * 16 + m) * S_LEN + s;
            int tok = x64 ? x[2 * ii] : x[ii];
            tok = (unsigned)tok < VOCAB ? tok : 0;
            xO[i] = tok * 512;
        }
    }
    for (int i = tid; i < 2 * 2 * 2048; i += 512) ((unsigned short*)hB)[i] = 0;
    float c[4] = {0.f, 0.f, 0.f, 0.f};
    __syncthreads();

    const int se0  = dir ? (S_LEN - 1) : 0;
    const int step = dir ? -1 : 1;
    const int u0   = 16 * wv + quad;

    // pxv lane base: element ((dir*VOCABP + v)*128 + u)*4; v enters via xO
    const float* pxvL = &g_pxv[(long)dir * VOCABP * 512 + u0 * 4];

    f32x4 pxA[4], pxB[4];
    {
        const int o0 = xO[se0 * 16 + m16];
        #pragma unroll
        for (int t = 0; t < 4; t++) pxA[t] = *(const f32x4*)(pxvL + o0 + 16 * t);
        const int se1 = (S_LEN > 1) ? se0 + step : se0;
        const int o1 = xO[se1 * 16 + m16];
        #pragma unroll
        for (int t = 0; t < 4; t++) pxB[t] = *(const f32x4*)(pxvL + o1 + 16 * t);
    }

    // incremental hs store base: ((se*16+bg)*128 + u0)*16 + m16, tiles at
    // +0,+64,+128,+192 floats; per-step delta = step*32768 floats
    float* hsp = &g_hs[dir][((long)(se0 * 16 + bg) * 128 + u0) * 16 + m16];
    const long hsd = (long)step * 32768;

    int itv = 0, sev = se0;

    for (int it = 0; it < S_LEN; it += 2) {
        SCAN_STEP(0, pxA)      // even step: read hB[0], write hB[1]
        SCAN_STEP(1, pxB)      // odd step:  read hB[1], write hB[0]
    }
}

// -------------------------------------------------------------------------
// Bulk emission from hs layout: block = (s,bg) tile [128u x 16m], staged in
// LDS; thread (m, j<9) dots 256-k. em[r*9+j] includes bout.
// -------------------------------------------------------------------------
__global__ __launch_bounds__(256, 4) void emission_kernel()
{
    __shared__ float hfL[2048], hbL[2048];
    __shared__ float Wsh[T_TAG][256];
    __shared__ float bo[T_TAG];
    const int tid = threadIdx.x, blk = blockIdx.x;   // 0..8191 = s*16+bg
    for (int i = tid; i < T_TAG * 256; i += 256) Wsh[i >> 8][i & 255] = g_wout[i];
    if (tid < T_TAG) bo[tid] = g_bout[tid];
    const float* hf = &g_hs[0][(long)blk * 2048];
    const float* hb = &g_hs[1][(long)blk * 2048];
    for (int i = tid; i < 2048; i += 256) { hfL[i] = hf[i]; hbL[i] = hb[i]; }
    __syncthreads();

    const int m = tid & 15, j = tid >> 4;
    if (j < T_TAG) {
        float acc = bo[j];
        #pragma unroll 4
        for (int u = 0; u < 128; u++)
            acc += hfL[u * 16 + m] * Wsh[j][u] + hbL[u * 16 + m] * Wsh[j][128 + u];
        const int r = (blk >> 4) * 256 + (blk & 15) * 16 + m;   // s*256 + b
        g_em[(long)r * T_TAG + j] = scrub0(acc);
    }
}

// -------------------------------------------------------------------------
// Viterbi: 1 wave per batch element (lanes 0..8 = tags), score broadcast via
// wave shfl — NO per-step barrier. Strict-> argmax = jnp first-max.
// -------------------------------------------------------------------------
__global__ __launch_bounds__(256, 2)
void viterbi_kernel(float* __restrict__ out, int out_size)
{
    __shared__ unsigned char bp[4][S_LEN][T_TAG];
    const int wid  = threadIdx.x >> 6;
    const int lane = threadIdx.x & 63;
    const int b  = blockIdx.x * 4 + wid;
    const int jj = (lane < T_TAG) ? lane : 0;

    float tcol[T_TAG];
    #pragma unroll
    for (int i = 0; i < T_TAG; i++) tcol[i] = g_trans[i * T_TAG + jj];

    float score[T_TAG];
    {
        const float m0 = g_maskf[b * S_LEN + 0];
        #pragma unroll
        for (int i = 0; i < T_TAG; i++)
            score[i] = g_start[i] + g_em[(long)b * T_TAG + i] * m0;
    }
    float e = g_em[((long)1 * B_SZ + b) * T_TAG + jj];
    float m = g_maskf[b * S_LEN + 1];

    for (int s = 1; s < S_LEN; s++) {
        float en = 0.f, mn = 0.f;
        if (s + 1 < S_LEN) {   // prefetch next step
            en = g_em[((long)(s + 1) * B_SZ + b) * T_TAG + jj];
            mn = g_maskf[b * S_LEN + s + 1];
        }
        float best = score[0] + tcol[0];
        int arg = 0;
        #pragma unroll
        for (int i = 1; i < T_TAG; i++) {
            const float cnd = score[i] + tcol[i];
            if (cnd > best) { best = cnd; arg = i; }
        }
        float ns; int nbp;
        if (m > 0.f) { ns = best + e * m; nbp = arg; }
        else         { ns = score[jj];    nbp = jj;  }
        if (lane < T_TAG) bp[wid][s][jj] = (unsigned char)nbp;
        #pragma unroll
        for (int i = 0; i < T_TAG; i++) score[i] = __shfl(ns, i, 64);
        e = en; m = mn;
    }
    #pragma unroll
    for (int i = 0; i < T_TAG; i++) score[i] += g_end[i];

    __syncthreads();   // bp visible for backtrace

    if (lane == 0) {
        float bs = score[0]; int last = 0;
        #pragma unroll
        for (int i = 1; i < T_TAG; i++)
            if (score[i] > bs) { bs = score[i]; last = i; }
        {
            const unsigned u = __float_as_uint(bs);
            if (((u >> 23) & 0xFFu) == 0xFFu) bs = -100.f;
        }
        if ((long)B_SZ * S_LEN + b < out_size)
            out[(long)B_SZ * S_LEN + b] = bs;
        int tag = last;
        if (tag < 0) tag = 0; if (tag > 8) tag = 8;
        out[(long)b * S_LEN + (S_LEN - 1)] = (float)tag;
        for (int s2 = S_LEN - 1; s2 >= 1; s2--) {
            tag = bp[wid][s2][tag];
            if (tag < 0) tag = 0; if (tag > 8) tag = 8;
            out[(long)b * S_LEN + (s2 - 1)] = (float)tag;
        }
    }
}

// -------------------------------------------------------------------------
extern "C" void kernel_launch(void* const* d_in, const int* in_sizes, int n_in,
                              void* d_out, int out_size, void* d_ws, size_t ws_size,
                              hipStream_t stream) {
    const int* x = (const int*)d_in[0];
    float* out = (float*)d_out;

    convert_kernel<<<512, 256, 0, stream>>>(
        d_in[1], d_in[2], d_in[3], d_in[4], d_in[5], d_in[6],
        d_in[7], d_in[8], d_in[9], d_in[10], d_in[11], d_in[12],
        d_in[13], d_in[14], d_in[15], out, out_size);
    pxv_gemm<<<dim3((VOCABP / 16), 2), 512, 0, stream>>>();
    scan_mfma<<<dim3(16, 2), 512, 0, stream>>>(x);
    emission_kernel<<<8192, 256, 0, stream>>>();
    viterbi_kernel<<<64, 256, 0, stream>>>(out, out_size);
}